// Round 1
// baseline (3079.947 us; speedup 1.0000x reference)
//
#include <hip/hip_runtime.h>
#include <stdint.h>
#include <math.h>

#define NALPH 128
#define NEMB  128
#define NST   512
#define BATCH 256
#define TLEN  256
#define FANIN 640   // NEMB + NST

__device__ __forceinline__ float bf2f(uint32_t lo16) {
  // raw bf16 bits in low 16 -> float (exact)
  return __uint_as_float(lo16 << 16);
}
__device__ __forceinline__ uint16_t f2bf(float x) {
  uint32_t u = __float_as_uint(x);
  u += 0x7fffu + ((u >> 16) & 1u);   // round-to-nearest-even
  return (uint16_t)(u >> 16);
}

// ---------------------------------------------------------------------------
// k_prep: three tiny jobs selected by blockIdx
//   [0,256)     G[tok*512+n]   = b_in[n] + sum_e emb[tok,e]*W_in[n,e]
//   [256,1280)  WsT[m*512+n]   = bf16(W_in[n*640 + 128 + m])   (W_s transposed)
//   [1280,1536) WoT[m*128+a]   = W_out[a*512+m]                (W_out transposed)
// ---------------------------------------------------------------------------
__global__ __launch_bounds__(256) void k_prep(
    const float* __restrict__ emb, const float* __restrict__ W_in,
    const float* __restrict__ b_in, const float* __restrict__ W_out,
    float* __restrict__ G, uint16_t* __restrict__ WsT, float* __restrict__ WoT)
{
  int bid = blockIdx.x, tid = threadIdx.x;
  if (bid < 256) {
    int idx = bid * 256 + tid;           // tok*512 + n
    int tok = idx >> 9, n = idx & 511;
    const float* er = emb + tok * NEMB;
    const float* wr = W_in + (size_t)n * FANIN;
    float acc = b_in[n];
#pragma unroll 8
    for (int e = 0; e < NEMB; ++e) acc += er[e] * wr[e];
    G[idx] = acc;
  } else if (bid < 1280) {
    int j = (bid - 256) * 256 + tid;     // j = m*512 + n
    int n = j & 511, m = j >> 9;
    WsT[j] = f2bf(W_in[(size_t)n * FANIN + NEMB + m]);
  } else {
    int j = (bid - 1280) * 256 + tid;    // j = m*128 + a
    int a = j & 127, m = j >> 7;
    WoT[j] = W_out[(size_t)a * NST + m];
  }
}

// ---------------------------------------------------------------------------
// k_rec: one block per batch row, 256 threads, thread owns n0=2*tid, n0+1.
// state (fp32) double-buffered in LDS; W_s streamed from L2 as bf16 (coalesced
// ushort2 per lane per m). states written out as bf16.
// ---------------------------------------------------------------------------
__global__ __launch_bounds__(256) void k_rec(
    const int* __restrict__ w, const float* __restrict__ G,
    const uint16_t* __restrict__ WsT, uint16_t* __restrict__ states)
{
  __shared__ float st[2][NST];
  int tid = threadIdx.x;
  int row = blockIdx.x;
  int n0 = tid * 2;
  st[0][n0] = 0.f; st[0][n0 + 1] = 0.f;
  __syncthreads();

  const int* wr = w + row * TLEN;
  uint16_t* srow = states + (size_t)row * TLEN * NST;
  const uint32_t* wbase = (const uint32_t*)WsT + tid;  // row m at wbase[m*256]
  int p = 0;

  for (int t = 0; t < TLEN; ++t) {
    int tok = wr[t];
    const float* g = G + tok * NST;
    float a0 = g[n0], a1 = g[n0 + 1];
    const float* sp = st[p];
#pragma unroll 8
    for (int m = 0; m < NST; ++m) {
      float s = sp[m];                   // LDS broadcast (same addr all lanes)
      uint32_t wv = wbase[m * 256];      // two bf16 weights, coalesced 256B/wave
      a0 += s * bf2f(wv & 0xffffu);
      a1 += s * bf2f(wv >> 16);
    }
    float s0 = tanhf(a0), s1 = tanhf(a1);
    st[p ^ 1][n0] = s0; st[p ^ 1][n0 + 1] = s1;
    srow[n0] = f2bf(s0); srow[n0 + 1] = f2bf(s1);
    srow += NST;
    __syncthreads();                     // writes to st[p^1] visible; sp fully read
    p ^= 1;
  }
}

// ---------------------------------------------------------------------------
// k_out: y[bt,a] = b_out[a] + sum_m states[bt,m] * W_out[a,m]
// block = 256 thr handles 16 bt-rows; states tile staged to LDS as fp32;
// WoT reads coalesced (lanes 0..127) / L1-replay (128..255).
// ---------------------------------------------------------------------------
__global__ __launch_bounds__(256) void k_out(
    const uint16_t* __restrict__ states, const float* __restrict__ WoT,
    const float* __restrict__ b_out, float* __restrict__ y)
{
  __shared__ float sl[16 * NST];         // 32 KB
  int tid = threadIdx.x;
  size_t bt0 = (size_t)blockIdx.x * 16;
  const uint32_t* sp = (const uint32_t*)(states + bt0 * NST);
  for (int i = tid; i < 16 * NST / 2; i += 256) {
    uint32_t v = sp[i];
    sl[2 * i]     = bf2f(v & 0xffffu);
    sl[2 * i + 1] = bf2f(v >> 16);
  }
  __syncthreads();

  int a = tid & 127, gidx = tid >> 7;    // gidx in {0,1}: rows [g*8, g*8+8)
  const float* slg = sl + (gidx * 8) * NST;
  float acc[8];
#pragma unroll
  for (int j = 0; j < 8; ++j) acc[j] = 0.f;

  for (int m = 0; m < NST; m += 2) {
    float w0 = WoT[m * 128 + a];
    float w1 = WoT[(m + 1) * 128 + a];
#pragma unroll
    for (int j = 0; j < 8; ++j) {
      // consecutive m -> compiler merges to ds_read_b64, broadcast across wave
      acc[j] += w0 * slg[j * NST + m] + w1 * slg[j * NST + m + 1];
    }
  }
  float bo = b_out[a];
#pragma unroll
  for (int j = 0; j < 8; ++j)
    y[(bt0 + gidx * 8 + j) * 128 + a] = acc[j] + bo;
}

// ---------------------------------------------------------------------------
extern "C" void kernel_launch(void* const* d_in, const int* in_sizes, int n_in,
                              void* d_out, int out_size, void* d_ws, size_t ws_size,
                              hipStream_t stream) {
  const int*   w     = (const int*)d_in[0];     // 256*256 tokens (int32)
  const float* emb   = (const float*)d_in[1];   // 128*128
  const float* W_in  = (const float*)d_in[2];   // 512*640
  const float* b_in  = (const float*)d_in[3];   // 512
  const float* W_out = (const float*)d_in[4];   // 128*512
  const float* b_out = (const float*)d_in[5];   // 128
  float* y = (float*)d_out;                     // 256*256*128 fp32

  char* ws = (char*)d_ws;
  float*    G      = (float*)ws;                         // 256 KB
  uint16_t* WsT    = (uint16_t*)(ws + (256 << 10));      // 512 KB
  float*    WoT    = (float*)(ws + (768 << 10));         // 256 KB
  uint16_t* states = (uint16_t*)(ws + (1024 << 10));     // 64 MB (bf16)

  k_prep<<<1536, 256, 0, stream>>>(emb, W_in, b_in, W_out, G, WsT, WoT);
  k_rec <<<BATCH, 256, 0, stream>>>(w, G, WsT, states);
  k_out <<<BATCH * TLEN / 16, 256, 0, stream>>>(states, WoT, b_out, y);
}

// Round 2
// 496.432 us; speedup vs baseline: 6.2042x; 6.2042x over previous
//
#include <hip/hip_runtime.h>
#include <stdint.h>
#include <math.h>

#define NALPH 128
#define NEMB  128
#define NST   512
#define BATCH 256
#define TLEN  256
#define FANIN 640   // NEMB + NST

__device__ __forceinline__ float bf2f(uint32_t lo16) {
  return __uint_as_float(lo16 << 16);
}
__device__ __forceinline__ uint16_t f2bf(float x) {
  uint32_t u = __float_as_uint(x);
  u += 0x7fffu + ((u >> 16) & 1u);   // RNE
  return (uint16_t)(u >> 16);
}

#if __has_builtin(__builtin_amdgcn_sdot4)
#define SDOT4(a, b, c) __builtin_amdgcn_sdot4((a), (b), (c), false)
#else
__device__ __forceinline__ int SDOT4(int a, int b, int c) {
  c += (int)(signed char)(a)       * (int)(signed char)(b);
  c += (int)(signed char)(a >> 8)  * (int)(signed char)(b >> 8);
  c += (int)(signed char)(a >> 16) * (int)(signed char)(b >> 16);
  c += (int)(signed char)(a >> 24) * (int)(signed char)(b >> 24);
  return c;
}
#endif

// ---------------------------------------------------------------------------
// k_prep (1024 blocks x 256 thr):
//  [0,256)    G[tok*512+n] = b_in[n] + sum_e emb[tok,e]*W_in[n,e]   (fp32 exact)
//  [256,512)  WoT[m*128+a] = W_out[a*512+m]
//  [512,1024) per-row int8 quant of W_s: row n = bid-512
//             WqT[kg*512+n] = pack4(q[n][4kg..4kg+3]),  Sd[n] = maxabs_n/16129
// ---------------------------------------------------------------------------
__global__ __launch_bounds__(256) void k_prep(
    const float* __restrict__ emb, const float* __restrict__ W_in,
    const float* __restrict__ b_in, const float* __restrict__ W_out,
    float* __restrict__ G, float* __restrict__ WoT,
    int* __restrict__ WqT, float* __restrict__ Sd)
{
  int bid = blockIdx.x, tid = threadIdx.x;
  if (bid < 256) {
    int idx = bid * 256 + tid;           // tok*512 + n
    int tok = idx >> 9, n = idx & 511;
    const float* er = emb + tok * NEMB;
    const float* wr = W_in + (size_t)n * FANIN;
    float acc = b_in[n];
#pragma unroll 8
    for (int e = 0; e < NEMB; ++e) acc += er[e] * wr[e];
    G[idx] = acc;
  } else if (bid < 512) {
    int j = (bid - 256) * 256 + tid;     // j = m*128 + a
    int a = j & 127, m = j >> 7;
    WoT[j] = W_out[(size_t)a * NST + m];
  } else {
    int n = bid - 512;                   // W_s row
    __shared__ float smax[128];
    float lw[4]; float m = 0.f;
    if (tid < 128) {
      const float* wr = W_in + (size_t)n * FANIN + NEMB + tid * 4;
#pragma unroll
      for (int i = 0; i < 4; ++i) { lw[i] = wr[i]; m = fmaxf(m, fabsf(lw[i])); }
      smax[tid] = m;
    }
    __syncthreads();
    for (int s2 = 64; s2 > 0; s2 >>= 1) {
      if (tid < s2) smax[tid] = fmaxf(smax[tid], smax[tid + s2]);
      __syncthreads();
    }
    float mx = smax[0];
    if (tid < 128) {
      float r = 127.f / mx;
      uint32_t pk = 0;
#pragma unroll
      for (int i = 0; i < 4; ++i) {
        int q = (int)rintf(lw[i] * r);
        q = q < -127 ? -127 : (q > 127 ? 127 : q);
        pk |= (uint32_t)(q & 0xff) << (8 * i);
      }
      WqT[tid * NST + n] = (int)pk;
    }
    if (tid == 0) Sd[n] = mx / 16129.0f;  // mx/(127*127)
  }
}

// ---------------------------------------------------------------------------
// k_rec: 256 blocks (1 batch row each) x 512 threads (1 state col each).
// W_s int8 register-resident (128 dwords/thread). Inner loop: 32 broadcast
// ds_read_b128 + 128 v_dot4_i32_i8. One barrier/step, i8 state double-buffered.
// ---------------------------------------------------------------------------
__global__ __launch_bounds__(512, 2) void k_rec(
    const int* __restrict__ w, const float* __restrict__ G,
    const int* __restrict__ WqT, const float* __restrict__ Sd,
    uint16_t* __restrict__ states)
{
  __shared__ __align__(16) signed char qs[2][NST];
  int tid = threadIdx.x;                 // owns col n = tid
  int row = blockIdx.x;

  int wq[128];
#pragma unroll
  for (int j = 0; j < 128; ++j) wq[j] = WqT[j * NST + tid];  // coalesced
  float dn = Sd[tid];

  qs[0][tid] = 0;
  __syncthreads();

  const int* wr = w + row * TLEN;
  uint16_t* srow = states + (size_t)row * TLEN * NST + tid;

  int tok = wr[0];
  float g = G[tok * NST + tid];
  int p = 0;
  for (int t = 0; t < TLEN; ++t) {
    int tok_n = (t < TLEN - 1) ? wr[t + 1] : 0;
    float g_n = G[tok_n * NST + tid];    // prefetch next step's fin
    const int4* sp = (const int4*)qs[p];
    int acc = 0;
#pragma unroll
    for (int j = 0; j < 32; ++j) {
      int4 sv = sp[j];                   // broadcast b128, conflict-free
      acc = SDOT4(wq[4 * j + 0], sv.x, acc);
      acc = SDOT4(wq[4 * j + 1], sv.y, acc);
      acc = SDOT4(wq[4 * j + 2], sv.z, acc);
      acc = SDOT4(wq[4 * j + 3], sv.w, acc);
    }
    float a = g + (float)acc * dn;
    a = fminf(fmaxf(a, -15.f), 15.f);
    float e = __expf(2.f * a);           // v_exp-based tanh
    float s = (e - 1.f) / (e + 1.f);
    srow[(size_t)t * NST] = f2bf(s);
    qs[p ^ 1][tid] = (signed char)(int)rintf(s * 127.f);
    __syncthreads();
    g = g_n;
    p ^= 1;
  }
}

// ---------------------------------------------------------------------------
// k_out: y[bt,a] = b_out[a] + sum_m states[bt,m] * W_out[a,m]
// ---------------------------------------------------------------------------
__global__ __launch_bounds__(256) void k_out(
    const uint16_t* __restrict__ states, const float* __restrict__ WoT,
    const float* __restrict__ b_out, float* __restrict__ y)
{
  __shared__ float sl[16 * NST];         // 32 KB
  int tid = threadIdx.x;
  size_t bt0 = (size_t)blockIdx.x * 16;
  const uint32_t* sp = (const uint32_t*)(states + bt0 * NST);
  for (int i = tid; i < 16 * NST / 2; i += 256) {
    uint32_t v = sp[i];
    sl[2 * i]     = bf2f(v & 0xffffu);
    sl[2 * i + 1] = bf2f(v >> 16);
  }
  __syncthreads();

  int a = tid & 127, gidx = tid >> 7;
  const float* slg = sl + (gidx * 8) * NST;
  float acc[8];
#pragma unroll
  for (int j = 0; j < 8; ++j) acc[j] = 0.f;

  for (int m = 0; m < NST; m += 2) {
    float w0 = WoT[m * 128 + a];
    float w1 = WoT[(m + 1) * 128 + a];
#pragma unroll
    for (int j = 0; j < 8; ++j)
      acc[j] += w0 * slg[j * NST + m] + w1 * slg[j * NST + m + 1];
  }
  float bo = b_out[a];
#pragma unroll
  for (int j = 0; j < 8; ++j)
    y[(bt0 + gidx * 8 + j) * 128 + a] = acc[j] + bo;
}

// ---------------------------------------------------------------------------
extern "C" void kernel_launch(void* const* d_in, const int* in_sizes, int n_in,
                              void* d_out, int out_size, void* d_ws, size_t ws_size,
                              hipStream_t stream) {
  const int*   w     = (const int*)d_in[0];
  const float* emb   = (const float*)d_in[1];
  const float* W_in  = (const float*)d_in[2];
  const float* b_in  = (const float*)d_in[3];
  const float* W_out = (const float*)d_in[4];
  const float* b_out = (const float*)d_in[5];
  float* y = (float*)d_out;

  char* ws = (char*)d_ws;
  float*    G      = (float*)ws;                        // 256 KB
  float*    WoT    = (float*)(ws + (256 << 10));        // 256 KB
  int*      WqT    = (int*)(ws + (512 << 10));          // 256 KB
  float*    Sd     = (float*)(ws + (768 << 10));        // 2 KB
  uint16_t* states = (uint16_t*)(ws + (1024 << 10));    // 64 MB bf16

  k_prep<<<1024, 256, 0, stream>>>(emb, W_in, b_in, W_out, G, WoT, WqT, Sd);
  k_rec <<<BATCH, 512, 0, stream>>>(w, G, WqT, Sd, states);
  k_out <<<BATCH * TLEN / 16, 256, 0, stream>>>(states, WoT, b_out, y);
}

// Round 3
// 465.469 us; speedup vs baseline: 6.6169x; 1.0665x over previous
//
#include <hip/hip_runtime.h>
#include <stdint.h>
#include <math.h>

#define NALPH 128
#define NEMB  128
#define NST   512
#define BATCH 256
#define TLEN  256
#define FANIN 640   // NEMB + NST

__device__ __forceinline__ uint16_t f2bf(float x) {
  uint32_t u = __float_as_uint(x);
  u += 0x7fffu + ((u >> 16) & 1u);
  return (uint16_t)(u >> 16);
}

#if __has_builtin(__builtin_amdgcn_sdot4)
#define SDOT4(a, b, c) __builtin_amdgcn_sdot4((a), (b), (c), false)
#else
__device__ __forceinline__ int SDOT4(int a, int b, int c) {
  c += (int)(signed char)(a)       * (int)(signed char)(b);
  c += (int)(signed char)(a >> 8)  * (int)(signed char)(b >> 8);
  c += (int)(signed char)(a >> 16) * (int)(signed char)(b >> 16);
  c += (int)(signed char)(a >> 24) * (int)(signed char)(b >> 24);
  return c;
}
#endif

// ---------------------------------------------------------------------------
// k_prep (896 blocks x 256 thr):
//  [0,256)    G[tok*512+n] = b_in[n] + sum_e emb[tok,e]*W_in[n,e]  (fp32, float4)
//  [256,768)  W_s row-quant:  WqT[kg*512+n] = pack4 i8, Sd[n] = mx_n/16129
//  [768,896)  W_out row-quant: WoQ[kg*128+a] = pack4 i8, So[a] = mx_a/16129
// ---------------------------------------------------------------------------
__global__ __launch_bounds__(256) void k_prep(
    const float* __restrict__ emb, const float* __restrict__ W_in,
    const float* __restrict__ b_in, const float* __restrict__ W_out,
    float* __restrict__ G, int* __restrict__ WqT, float* __restrict__ Sd,
    int* __restrict__ WoQ, float* __restrict__ So)
{
  int bid = blockIdx.x, tid = threadIdx.x;
  if (bid < 256) {
    int idx = bid * 256 + tid;           // tok*512 + n
    int tok = idx >> 9, n = idx & 511;
    const float4* er4 = (const float4*)(emb + tok * NEMB);
    const float4* wr4 = (const float4*)(W_in + (size_t)n * FANIN);
    float acc = b_in[n];
#pragma unroll 8
    for (int e = 0; e < NEMB / 4; ++e) {
      float4 av = er4[e], bv = wr4[e];
      acc += av.x * bv.x + av.y * bv.y + av.z * bv.z + av.w * bv.w;
    }
    G[idx] = acc;
  } else if (bid < 768) {
    int n = bid - 256;                   // W_s row
    __shared__ float smax[128];
    float lw[4]; float m = 0.f;
    if (tid < 128) {
      const float* wr = W_in + (size_t)n * FANIN + NEMB + tid * 4;
#pragma unroll
      for (int i = 0; i < 4; ++i) { lw[i] = wr[i]; m = fmaxf(m, fabsf(lw[i])); }
      smax[tid] = m;
    }
    __syncthreads();
    for (int s2 = 64; s2 > 0; s2 >>= 1) {
      if (tid < s2) smax[tid] = fmaxf(smax[tid], smax[tid + s2]);
      __syncthreads();
    }
    float mx = smax[0];
    if (tid < 128) {
      float r = 127.f / mx;
      uint32_t pk = 0;
#pragma unroll
      for (int i = 0; i < 4; ++i) {
        int q = (int)rintf(lw[i] * r);
        q = q < -127 ? -127 : (q > 127 ? 127 : q);
        pk |= (uint32_t)(q & 0xff) << (8 * i);
      }
      WqT[tid * NST + n] = (int)pk;
    }
    if (tid == 0) Sd[n] = mx / 16129.0f;
  } else {
    int a = bid - 768;                   // W_out row
    __shared__ float smax[128];
    float lw[4]; float m = 0.f;
    if (tid < 128) {
      const float* wr = W_out + (size_t)a * NST + tid * 4;
#pragma unroll
      for (int i = 0; i < 4; ++i) { lw[i] = wr[i]; m = fmaxf(m, fabsf(lw[i])); }
      smax[tid] = m;
    }
    __syncthreads();
    for (int s2 = 64; s2 > 0; s2 >>= 1) {
      if (tid < s2) smax[tid] = fmaxf(smax[tid], smax[tid + s2]);
      __syncthreads();
    }
    float mx = smax[0];
    if (tid < 128) {
      float r = 127.f / mx;
      uint32_t pk = 0;
#pragma unroll
      for (int i = 0; i < 4; ++i) {
        int q = (int)rintf(lw[i] * r);
        q = q < -127 ? -127 : (q > 127 ? 127 : q);
        pk |= (uint32_t)(q & 0xff) << (8 * i);
      }
      WoQ[tid * 128 + a] = (int)pk;
    }
    if (tid == 0) So[a] = mx / 16129.0f;
  }
}

// ---------------------------------------------------------------------------
// k_rec (fused): 256 blocks (1 batch row) x 1024 threads.
// thread t: col n = t&511, K-half h = t>>9. wq[64] i8 dwords in VGPRs.
// Also owns y-slice: output a = n&127, K-quarter ksub = n>>7, woq[16] dwords.
// Per step: stream qs[p] (16 broadcast b128) -> 64 recur dot4 + 16 y dot4
// (y reuses the same state registers; y lags one step). 2 barriers/step.
// ---------------------------------------------------------------------------
__global__ __launch_bounds__(1024, 4) void k_rec(
    const int* __restrict__ w, const float* __restrict__ G,
    const int* __restrict__ WqT, const float* __restrict__ Sd,
    const int* __restrict__ WoQ, const float* __restrict__ So,
    const float* __restrict__ b_out, float* __restrict__ y)
{
  __shared__ __align__(16) signed char qs[2][NST];
  __shared__ int pr[1024];
  __shared__ int py[1024];

  int t = threadIdx.x;
  int row = blockIdx.x;
  int n = t & 511;
  int h = t >> 9;
  int a = n & 127;
  int ksub = __builtin_amdgcn_readfirstlane(n >> 7);  // wave-uniform -> scalarize

  int wq[64];
#pragma unroll
  for (int j = 0; j < 64; ++j) wq[j] = WqT[(h * 64 + j) * NST + n];
  int woq[16];
#pragma unroll
  for (int j = 0; j < 16; ++j) woq[j] = WoQ[(h * 64 + ksub * 16 + j) * 128 + a];
  float dn = Sd[n];
  float so = So[a];
  float bo = b_out[a];

  if (t < NST) qs[0][t] = 0;
  __syncthreads();

  const int* wr = w + row * TLEN;
  float* yrow = y + (size_t)row * TLEN * 128;

  float g = G[wr[0] * NST + n];
  int p = 0;
  for (int tt = 0; tt < TLEN; ++tt) {
    // ---- phase A: dots on qs[p] (= s_{tt-1}) ----
    const int4* sp = (const int4*)&qs[p][h * 256];
    int ar0 = 0, ar1 = 0, ay = 0;
#pragma unroll
    for (int r = 0; r < 16; ++r) {
      int4 sv = sp[r];
      ar0 = SDOT4(wq[4 * r + 0], sv.x, ar0);
      ar1 = SDOT4(wq[4 * r + 1], sv.y, ar1);
      ar0 = SDOT4(wq[4 * r + 2], sv.z, ar0);
      ar1 = SDOT4(wq[4 * r + 3], sv.w, ar1);
      if ((r >> 2) == ksub) {          // wave-uniform scalar branch
        int j = (r & 3) * 4;
        ay = SDOT4(woq[j + 0], sv.x, ay);
        ay = SDOT4(woq[j + 1], sv.y, ay);
        ay = SDOT4(woq[j + 2], sv.z, ay);
        ay = SDOT4(woq[j + 3], sv.w, ay);
      }
    }
    // ---- phase B: publish partials ----
    pr[t] = ar0 + ar1;
    py[t] = ay;
    __syncthreads();

    // prefetch next fin (uniform token -> scalar load; coalesced G read)
    int tok_n = wr[(tt + 1) & (TLEN - 1)];
    float g_n = G[tok_n * NST + n];

    // ---- phase C ----
    if (t < NST) {
      int tot = ar0 + ar1 + pr[t + 512];
      float av = g + (float)tot * dn;
      av = fminf(fmaxf(av, -15.f), 15.f);
      float e = __expf(2.f * av);
      float s = (e - 1.f) / (e + 1.f);
      qs[p ^ 1][t] = (signed char)(int)rintf(s * 127.f);
    } else if (t < 640) {
      int aa = t - 512;
      int sum = py[aa]       + py[aa + 128] + py[aa + 256] + py[aa + 384]
              + py[aa + 512] + py[aa + 640] + py[aa + 768] + py[aa + 896];
      if (tt > 0) yrow[(size_t)(tt - 1) * 128 + aa] = (float)sum * so + bo;
    }
    __syncthreads();
    g = g_n;
    p ^= 1;
  }

  // ---- epilogue: y_255 from qs[p] (= s_255) ----
  {
    const int4* sp = (const int4*)&qs[p][h * 256];
    int ay = 0;
#pragma unroll
    for (int i = 0; i < 4; ++i) {
      int4 sv = sp[ksub * 4 + i];
      ay = SDOT4(woq[4 * i + 0], sv.x, ay);
      ay = SDOT4(woq[4 * i + 1], sv.y, ay);
      ay = SDOT4(woq[4 * i + 2], sv.z, ay);
      ay = SDOT4(woq[4 * i + 3], sv.w, ay);
    }
    py[t] = ay;
    __syncthreads();
    if (t >= 512 && t < 640) {
      int aa = t - 512;
      int sum = py[aa]       + py[aa + 128] + py[aa + 256] + py[aa + 384]
              + py[aa + 512] + py[aa + 640] + py[aa + 768] + py[aa + 896];
      yrow[(size_t)(TLEN - 1) * 128 + aa] = (float)sum * so + bo;
    }
  }
}

// ---------------------------------------------------------------------------
extern "C" void kernel_launch(void* const* d_in, const int* in_sizes, int n_in,
                              void* d_out, int out_size, void* d_ws, size_t ws_size,
                              hipStream_t stream) {
  const int*   w     = (const int*)d_in[0];
  const float* emb   = (const float*)d_in[1];
  const float* W_in  = (const float*)d_in[2];
  const float* b_in  = (const float*)d_in[3];
  const float* W_out = (const float*)d_in[4];
  const float* b_out = (const float*)d_in[5];
  float* y = (float*)d_out;

  char* ws = (char*)d_ws;
  float* G   = (float*)ws;                      // 256 KB
  int*   WqT = (int*)(ws + (256 << 10));        // 256 KB
  int*   WoQ = (int*)(ws + (512 << 10));        // 64 KB
  float* Sd  = (float*)(ws + (576 << 10));      // 2 KB
  float* So  = (float*)(ws + (580 << 10));      // 0.5 KB

  k_prep<<<896, 256, 0, stream>>>(emb, W_in, b_in, W_out, G, WqT, Sd, WoQ, So);
  k_rec <<<BATCH, 1024, 0, stream>>>(w, G, WqT, Sd, WoQ, So, b_out, y);
}